// Round 2
// 111.434 us; speedup vs baseline: 1.0027x; 1.0027x over previous
//
#include <hip/hip_runtime.h>

#define NATOMS 2048
#define R_DIM 512
#define P_DIM 256
#define S_DIM 4
#define NSTACKS 32
#define F_DIM 8192
#define KS 8                 // K splits
#define KSPAN (R_DIM / KS)   // 64
#define TR 64                // atoms per tile
#define TC 128               // cols per tile
#define KT 16                // k chunk
#define RT_TILES 11          // covers cnt_s up to 704 (mean 512, sd 19.4 — 9.9 sigma)

// DPP lane-permute as a VALU op (validated R6/R7):
//   0xB1 quad_perm[1,0,3,2]=xor1 ; 0x4E quad_perm[2,3,0,1]=xor2 ;
//   0x128 row_ror:8=xor8 ; 0x124 row_ror:4 (sum-reduce only) ;
//   0x104 row_shl:4 (lane i <- i+4) ; 0x114 row_shr:4 (lane i <- i-4).
// NEVER put DPP calls inside conditional expressions — compute both, select.
// Session laws (measured): grid-wide sync (cooperative OR manual spin) costs
// ~200us here (R8/R9) — never fuse across proj->feat. 128-thread proj blocks
// (R10) drop to 1.5 waves/SIMD and lose ~10us to exposed staging latency.
// R11/R12: xor16/xor32 via v_permlane{16,32}_swap_b32 (gfx950 VALU)
// instead of __shfl_xor's ds_bpermute — removes all LDS-pipe ops (~66/wave)
// and two ~100cy lgkmcnt round-trips per j-chain from the feat kernel.
// (R11 bench was a container-acquire failure, not a kernel result — resubmitted.)
#define DPPF(x, ctrl) \
  __int_as_float(__builtin_amdgcn_update_dpp( \
      __float_as_int(x), __float_as_int(x), (ctrl), 0xF, 0xF, false))

#if defined(__has_builtin)
#if __has_builtin(__builtin_amdgcn_permlane16_swap) && \
    __has_builtin(__builtin_amdgcn_permlane32_swap)
#define HAVE_PERMLANE_SWAP 1
#endif
#endif

// FWHT butterfly across lane^16 / lane^32.
// permlane16_swap(x,x): r[0] = own (even rows) / partner (odd rows), r[1] = complement;
// fmaf(sg, r[1], r[0]) == fmaf(sg, own, partner) bit-exactly for every lane.
__device__ __forceinline__ float bfly16(float x, float sg) {
#ifdef HAVE_PERMLANE_SWAP
  auto r = __builtin_amdgcn_permlane16_swap(__float_as_uint(x), __float_as_uint(x),
                                            false, false);
  return fmaf(sg, __uint_as_float(r[1]), __uint_as_float(r[0]));
#else
  return fmaf(sg, x, __shfl_xor(x, 16));
#endif
}
__device__ __forceinline__ float bfly32(float x, float sg) {
#ifdef HAVE_PERMLANE_SWAP
  auto r = __builtin_amdgcn_permlane32_swap(__float_as_uint(x), __float_as_uint(x),
                                            false, false);
  return fmaf(sg, __uint_as_float(r[1]), __uint_as_float(r[0]));
#else
  return fmaf(sg, x, __shfl_xor(x, 32));
#endif
}
// Sum-reduce across lane^16 / lane^32: own + partner = r[0] + r[1] for every lane.
__device__ __forceinline__ float redsum16(float x) {
#ifdef HAVE_PERMLANE_SWAP
  auto r = __builtin_amdgcn_permlane16_swap(__float_as_uint(x), __float_as_uint(x),
                                            false, false);
  return __uint_as_float(r[0]) + __uint_as_float(r[1]);
#else
  return x + __shfl_xor(x, 16);
#endif
}
__device__ __forceinline__ float redsum32(float x) {
#ifdef HAVE_PERMLANE_SWAP
  auto r = __builtin_amdgcn_permlane32_swap(__float_as_uint(x), __float_as_uint(x),
                                            false, false);
  return __uint_as_float(r[0]) + __uint_as_float(r[1]);
#else
  return x + __shfl_xor(x, 32);
#endif
}

// ws layout: [16384, +16MB) : projp float[KS][2048][256]

// grid: bid = ks(8) | cb(1) | (rt,s): 8*2*11*4 = 704 blocks, 256 threads.
__global__ __launch_bounds__(256) void sorf_proj_kernel(
    const float* __restrict__ rep, const float* __restrict__ reductors,
    const int* __restrict__ charges, float* __restrict__ projp,
    float* __restrict__ out) {
  int bid = blockIdx.x;
  int ks = bid & 7;
  int cb = (bid >> 3) & 1;
  int r2 = bid >> 4;            // 0..43
  int rt = r2 % RT_TILES;
  int s  = r2 / RT_TILES;

  int t = threadIdx.x;
  int lane = t & 63, wave = t >> 6;
  if (bid == 0 && t < 32) out[t] = 0.f;  // d_out re-poisoned each launch

  // ---- in-block charge scan: row list for this (s, rt) tile ----
  // thread t owns atoms 8t..8t+7 (ascending thread order == atom order).
  __shared__ int rowsL[TR];
  __shared__ int wtot[4];
  int4 c0v = ((const int4*)charges)[t * 2];
  int4 c1v = ((const int4*)charges)[t * 2 + 1];
  int fl[8];
  fl[0] = (c0v.x == s); fl[1] = (c0v.y == s); fl[2] = (c0v.z == s); fl[3] = (c0v.w == s);
  fl[4] = (c1v.x == s); fl[5] = (c1v.y == s); fl[6] = (c1v.z == s); fl[7] = (c1v.w == s);
  int cnt8 = ((fl[0] + fl[1]) + (fl[2] + fl[3])) + ((fl[4] + fl[5]) + (fl[6] + fl[7]));
  int scan = cnt8;                       // inclusive scan over lanes
#pragma unroll
  for (int o = 1; o < 64; o <<= 1) {
    int y = __shfl_up(scan, o);
    if (lane >= o) scan += y;
  }
  if (lane == 63) wtot[wave] = scan;
  __syncthreads();
  int wb = 0;
#pragma unroll
  for (int w = 0; w < 4; ++w) wb += (w < wave) ? wtot[w] : 0;
  int total = (wtot[0] + wtot[1]) + (wtot[2] + wtot[3]);
  int lo = rt * TR;
  int nrows = min(TR, total - lo);       // uniform across block
  if (nrows <= 0) return;
  if (t >= nrows && t < TR) rowsL[t] = 0;  // dummy rows for staging reads (stores guarded)
  int pos = wb + scan - cnt8;            // exclusive prefix = rank of this thread's 1st match
#pragma unroll
  for (int i = 0; i < 8; ++i) {
    if (fl[i]) {
      int rel = pos - lo;
      if (rel >= 0 && rel < TR) rowsL[rel] = t * 8 + i;
      pos++;
    }
  }
  __syncthreads();

  // ---- 64 x 128 tile GEMM over this ks K-slice (4x8 register tile) ----
  __shared__ float As[KT][TR + 4];   // stride 68: 16B-aligned rows, 2-way aliasing (free)
  __shared__ float Bs[KT][TC];       // quads read at tx*4 and 64+tx*4: 2-way (free)

  int ar = t >> 2;        // A row staged by this thread
  int aq = t & 3;         // k-quad within KT chunk
  const float* aSrc = rep + (size_t)rowsL[ar] * R_DIM + ks * KSPAN + aq * 4;
  int kb = t >> 4;        // B k row
  int cc = (t & 15) * 4;  // B col quad (plus +64 partner)
  const float* bSrc = reductors + ((size_t)s * R_DIM + ks * KSPAN + kb) * P_DIM + cb * TC + cc;

  int ty = t >> 4, tx = t & 15;
  int r0 = ty * 4;
  int c0 = tx * 4;        // cols c0..c0+3 and c0+64..c0+67

  float acc[4][8];
#pragma unroll
  for (int i = 0; i < 4; ++i)
#pragma unroll
    for (int j = 0; j < 8; ++j) acc[i][j] = 0.f;

  float4 a  = *(const float4*)aSrc;
  float4 b0 = *(const float4*)bSrc;
  float4 b1 = *(const float4*)(bSrc + 64);

#pragma unroll 1
  for (int k0 = 0; k0 < KSPAN; k0 += KT) {
    __syncthreads();   // previous iteration's LDS reads complete
    As[aq * 4 + 0][ar] = a.x;
    As[aq * 4 + 1][ar] = a.y;
    As[aq * 4 + 2][ar] = a.z;
    As[aq * 4 + 3][ar] = a.w;
    *(float4*)&Bs[kb][cc] = b0;
    *(float4*)&Bs[kb][cc + 64] = b1;
    __syncthreads();
    if (k0 + KT < KSPAN) {   // prefetch next chunk; latency overlaps compute below
      a  = *(const float4*)(aSrc + k0 + KT);
      b0 = *(const float4*)(bSrc + (size_t)(k0 + KT) * P_DIM);
      b1 = *(const float4*)(bSrc + (size_t)(k0 + KT) * P_DIM + 64);
    }
#pragma unroll
    for (int kk = 0; kk < KT; ++kk) {
      float4 aV = *(const float4*)&As[kk][r0];
      float4 bA = *(const float4*)&Bs[kk][c0];
      float4 bB = *(const float4*)&Bs[kk][c0 + 64];
      float av[4] = {aV.x, aV.y, aV.z, aV.w};
      float bv[8] = {bA.x, bA.y, bA.z, bA.w, bB.x, bB.y, bB.z, bB.w};
#pragma unroll
      for (int i = 0; i < 4; ++i)
#pragma unroll
        for (int j = 0; j < 8; ++j) acc[i][j] = fmaf(av[i], bv[j], acc[i][j]);
    }
  }

  // coalesced: 16 threads (tx) cover each 256B half-row segment
#pragma unroll
  for (int i = 0; i < 4; ++i) {
    int r = r0 + i;
    if (r < nrows) {
      float* dst = projp + ((size_t)ks * NATOMS + rowsL[r]) * P_DIM + cb * TC + c0;
      *(float4*)dst = make_float4(acc[i][0], acc[i][1], acc[i][2], acc[i][3]);
      *(float4*)(dst + 64) = make_float4(acc[i][4], acc[i][5], acc[i][6], acc[i][7]);
    }
  }
}

// grid: one block per atom; wave w handles stacks [w*8, w*8+8)
__global__ __launch_bounds__(256) void sorf_feat_kernel(
    const float* __restrict__ projp, const int* __restrict__ charges,
    const float* __restrict__ Dmat, const float* __restrict__ bias,
    const float* __restrict__ alpha, float* __restrict__ out) {
  const int atom = blockIdx.x;
  const int t = threadIdx.x;
  const int lane = t & 63;
  const int wave = t >> 6;
  const int s = charges[atom];

  // lane holds p = 4*lane+k; reduce the KS K-split partials in-register
  float4 p = *((const float4*)(projp + (size_t)atom * P_DIM) + lane);
#pragma unroll
  for (int ksi = 1; ksi < KS; ++ksi) {
    float4 q = *((const float4*)(projp + ((size_t)ksi * NATOMS + atom) * P_DIM) + lane);
    p.x += q.x; p.y += q.y; p.z += q.z; p.w += q.w;
  }

  const float sg1  = (lane & 1)  ? -1.f : 1.f;
  const float sg2  = (lane & 2)  ? -1.f : 1.f;
  const float sg4  = (lane & 4)  ? -1.f : 1.f;
  const float sg8  = (lane & 8)  ? -1.f : 1.f;
  const float sg16 = (lane & 16) ? -1.f : 1.f;
  const float sg32 = (lane & 32) ? -1.f : 1.f;
  const bool hi4 = (lane & 4) != 0;

  const float* Db = Dmat + (size_t)s * (NSTACKS * P_DIM);
  const float* bb = bias + (size_t)s * F_DIM;
  float accum = 0.f;

#pragma unroll 2
  for (int j = wave * 8; j < wave * 8 + 8; ++j) {
    float4 d  = *((const float4*)(Db + j * P_DIM) + lane);
    float4 bi = *((const float4*)(bb + j * P_DIM) + lane);
    float4 al = *((const float4*)(alpha + j * P_DIM) + lane);
    float x0 = (d.x >= 0.f) ? p.x : -p.x;
    float x1 = (d.y >= 0.f) ? p.y : -p.y;
    float x2 = (d.z >= 0.f) ? p.z : -p.z;
    float x3 = (d.w >= 0.f) ? p.w : -p.w;
    // FWHT bits 0,1 in-register
    float t0 = x0 + x1, t1 = x0 - x1, t2 = x2 + x3, t3 = x2 - x3;
    x0 = t0 + t2; x2 = t0 - t2; x1 = t1 + t3; x3 = t1 - t3;
    // xor1 (DPP)
    { float y0 = DPPF(x0, 0xB1), y1 = DPPF(x1, 0xB1), y2 = DPPF(x2, 0xB1), y3 = DPPF(x3, 0xB1);
      x0 = fmaf(sg1, x0, y0); x1 = fmaf(sg1, x1, y1);
      x2 = fmaf(sg1, x2, y2); x3 = fmaf(sg1, x3, y3); }
    // xor2 (DPP)
    { float y0 = DPPF(x0, 0x4E), y1 = DPPF(x1, 0x4E), y2 = DPPF(x2, 0x4E), y3 = DPPF(x3, 0x4E);
      x0 = fmaf(sg2, x0, y0); x1 = fmaf(sg2, x1, y1);
      x2 = fmaf(sg2, x2, y2); x3 = fmaf(sg2, x3, y3); }
    // xor4: both DPP shifts unconditionally, branchless select (validated R7)
    { float a0 = DPPF(x0, 0x104), a1 = DPPF(x1, 0x104), a2 = DPPF(x2, 0x104), a3 = DPPF(x3, 0x104);
      float b0 = DPPF(x0, 0x114), b1 = DPPF(x1, 0x114), b2 = DPPF(x2, 0x114), b3 = DPPF(x3, 0x114);
      float y0 = hi4 ? b0 : a0;
      float y1 = hi4 ? b1 : a1;
      float y2 = hi4 ? b2 : a2;
      float y3 = hi4 ? b3 : a3;
      x0 = fmaf(sg4, x0, y0); x1 = fmaf(sg4, x1, y1);
      x2 = fmaf(sg4, x2, y2); x3 = fmaf(sg4, x3, y3); }
    // xor8 (DPP row_ror:8)
    { float y0 = DPPF(x0, 0x128), y1 = DPPF(x1, 0x128), y2 = DPPF(x2, 0x128), y3 = DPPF(x3, 0x128);
      x0 = fmaf(sg8, x0, y0); x1 = fmaf(sg8, x1, y1);
      x2 = fmaf(sg8, x2, y2); x3 = fmaf(sg8, x3, y3); }
    // xor16 (v_permlane16_swap_b32 — VALU, no LDS pipe)
    x0 = bfly16(x0, sg16); x1 = bfly16(x1, sg16);
    x2 = bfly16(x2, sg16); x3 = bfly16(x3, sg16);
    // xor32 (v_permlane32_swap_b32 — VALU, no LDS pipe)
    x0 = bfly32(x0, sg32); x1 = bfly32(x1, sg32);
    x2 = bfly32(x2, sg32); x3 = bfly32(x3, sg32);
    // fwht norm 1/16; COEFF_NORM = 1.0 exactly
    accum += __cosf(fmaf(x0, 0.0625f, bi.x)) * al.x;
    accum += __cosf(fmaf(x1, 0.0625f, bi.y)) * al.y;
    accum += __cosf(fmaf(x2, 0.0625f, bi.z)) * al.z;
    accum += __cosf(fmaf(x3, 0.0625f, bi.w)) * al.w;
  }

  // wave sum-reduce (permutation-invariant)
  accum += DPPF(accum, 0xB1);
  accum += DPPF(accum, 0x4E);
  accum += DPPF(accum, 0x124);   // row_ror:4
  accum += DPPF(accum, 0x128);   // row_ror:8
  accum = redsum16(accum);       // lane^16 via permlane16_swap
  accum = redsum32(accum);       // lane^32 via permlane32_swap

  __shared__ float wsum[4];
  if (lane == 0) wsum[wave] = accum;
  __syncthreads();
  if (t == 0) {
    // FEAT_NORM = 1/64 exactly
    atomicAdd(out + (atom >> 6), 0.015625f * ((wsum[0] + wsum[1]) + (wsum[2] + wsum[3])));
  }
}

extern "C" void kernel_launch(void* const* d_in, const int* in_sizes, int n_in,
                              void* d_out, int out_size, void* d_ws, size_t ws_size,
                              hipStream_t stream) {
  const float* rep       = (const float*)d_in[0];
  const int*   charges   = (const int*)d_in[1];
  const float* reductors = (const float*)d_in[2];
  const float* Dmat      = (const float*)d_in[3];
  const float* bias      = (const float*)d_in[4];
  const float* alpha     = (const float*)d_in[5];
  float* out = (float*)d_out;

  float* projp = (float*)((char*)d_ws + 16384);

  sorf_proj_kernel<<<8 * 2 * RT_TILES * S_DIM, 256, 0, stream>>>(
      rep, reductors, charges, projp, out);
  sorf_feat_kernel<<<NATOMS, 256, 0, stream>>>(projp, charges, Dmat, bias, alpha, out);
}

// Round 3
// 103.247 us; speedup vs baseline: 1.0822x; 1.0793x over previous
//
#include <hip/hip_runtime.h>

#define NATOMS 2048
#define R_DIM 512
#define P_DIM 256
#define S_DIM 4
#define NSTACKS 32
#define F_DIM 8192
#define KS 8                 // K splits
#define KSPAN (R_DIM / KS)   // 64
#define TR 64                // atoms per tile
#define TC 128               // cols per tile
#define KT 16                // k chunk
#define RT_TILES 11          // covers cnt_s up to 704 (mean 512, sd 19.4 — 9.9 sigma)
#define SORT_PITCH (RT_TILES * TR)   // 704 sorted-atom slots per s
#define PAIRS_PER_S (SORT_PITCH / 2) // 352 feat blocks per s

// DPP lane-permute as a VALU op (validated R6/R7):
//   0xB1 quad_perm[1,0,3,2]=xor1 ; 0x4E quad_perm[2,3,0,1]=xor2 ;
//   0x128 row_ror:8=xor8 ; 0x124 row_ror:4 (sum-reduce only) ;
//   0x104 row_shl:4 (lane i <- i+4) ; 0x114 row_shr:4 (lane i <- i-4).
// NEVER put DPP calls inside conditional expressions — compute both, select.
// Session laws (measured): grid-wide sync (cooperative OR manual spin) costs
// ~200us here (R8/R9) — never fuse across proj->feat. 128-thread proj blocks
// (R10) drop to 1.5 waves/SIMD and lose ~10us to exposed staging latency.
// R11/R12: permlane{16,32}_swap for xor16/32 — NEUTRAL (feat is not
// LDS-pipe-bound; kept because bit-identical and strictly fewer pipes used).
// R13: feat is L2-load-bound (~213 MB of d/bi/al reads, >= VALU time).
// Proj exports the per-s sorted atom list (it already computes it); feat
// processes SAME-CHARGE ATOM PAIRS per block so each d/bi/al load feeds two
// FWHT chains: load traffic -46%, and the two chains give 2-way ILP in the
// serial butterfly dependency chain.
#define DPPF(x, ctrl) \
  __int_as_float(__builtin_amdgcn_update_dpp( \
      __float_as_int(x), __float_as_int(x), (ctrl), 0xF, 0xF, false))

#if defined(__has_builtin)
#if __has_builtin(__builtin_amdgcn_permlane16_swap) && \
    __has_builtin(__builtin_amdgcn_permlane32_swap)
#define HAVE_PERMLANE_SWAP 1
#endif
#endif

// FWHT butterfly across lane^16 / lane^32.
// permlane16_swap(x,x): r[0] = own (even rows) / partner (odd rows), r[1] = complement;
// fmaf(sg, r[1], r[0]) == fmaf(sg, own, partner) bit-exactly for every lane.
__device__ __forceinline__ float bfly16(float x, float sg) {
#ifdef HAVE_PERMLANE_SWAP
  auto r = __builtin_amdgcn_permlane16_swap(__float_as_uint(x), __float_as_uint(x),
                                            false, false);
  return fmaf(sg, __uint_as_float(r[1]), __uint_as_float(r[0]));
#else
  return fmaf(sg, x, __shfl_xor(x, 16));
#endif
}
__device__ __forceinline__ float bfly32(float x, float sg) {
#ifdef HAVE_PERMLANE_SWAP
  auto r = __builtin_amdgcn_permlane32_swap(__float_as_uint(x), __float_as_uint(x),
                                            false, false);
  return fmaf(sg, __uint_as_float(r[1]), __uint_as_float(r[0]));
#else
  return fmaf(sg, x, __shfl_xor(x, 32));
#endif
}
// Sum-reduce across lane^16 / lane^32: own + partner = r[0] + r[1] for every lane.
__device__ __forceinline__ float redsum16(float x) {
#ifdef HAVE_PERMLANE_SWAP
  auto r = __builtin_amdgcn_permlane16_swap(__float_as_uint(x), __float_as_uint(x),
                                            false, false);
  return __uint_as_float(r[0]) + __uint_as_float(r[1]);
#else
  return x + __shfl_xor(x, 16);
#endif
}
__device__ __forceinline__ float redsum32(float x) {
#ifdef HAVE_PERMLANE_SWAP
  auto r = __builtin_amdgcn_permlane32_swap(__float_as_uint(x), __float_as_uint(x),
                                            false, false);
  return __uint_as_float(r[0]) + __uint_as_float(r[1]);
#else
  return x + __shfl_xor(x, 32);
#endif
}

// ws layout:
//   [0, 16)        : scnt int[4]        (atom count per charge)
//   [64, 11328)    : sorted int[4][704] (atom ids in per-s scan order)
//   [16384, +16MB) : projp float[KS][2048][256]

// grid: bid = ks(8) | cb(1) | (rt,s): 8*2*11*4 = 704 blocks, 256 threads.
__global__ __launch_bounds__(256) void sorf_proj_kernel(
    const float* __restrict__ rep, const float* __restrict__ reductors,
    const int* __restrict__ charges, float* __restrict__ projp,
    int* __restrict__ scnt, int* __restrict__ sorted,
    float* __restrict__ out) {
  int bid = blockIdx.x;
  int ks = bid & 7;
  int cb = (bid >> 3) & 1;
  int r2 = bid >> 4;            // 0..43
  int rt = r2 % RT_TILES;
  int s  = r2 / RT_TILES;

  int t = threadIdx.x;
  int lane = t & 63, wave = t >> 6;
  if (bid == 0 && t < 32) out[t] = 0.f;  // d_out re-poisoned each launch

  // ---- in-block charge scan: row list for this (s, rt) tile ----
  // thread t owns atoms 8t..8t+7 (ascending thread order == atom order).
  __shared__ int rowsL[TR];
  __shared__ int wtot[4];
  int4 c0v = ((const int4*)charges)[t * 2];
  int4 c1v = ((const int4*)charges)[t * 2 + 1];
  int fl[8];
  fl[0] = (c0v.x == s); fl[1] = (c0v.y == s); fl[2] = (c0v.z == s); fl[3] = (c0v.w == s);
  fl[4] = (c1v.x == s); fl[5] = (c1v.y == s); fl[6] = (c1v.z == s); fl[7] = (c1v.w == s);
  int cnt8 = ((fl[0] + fl[1]) + (fl[2] + fl[3])) + ((fl[4] + fl[5]) + (fl[6] + fl[7]));
  int scan = cnt8;                       // inclusive scan over lanes
#pragma unroll
  for (int o = 1; o < 64; o <<= 1) {
    int y = __shfl_up(scan, o);
    if (lane >= o) scan += y;
  }
  if (lane == 63) wtot[wave] = scan;
  __syncthreads();
  int wb = 0;
#pragma unroll
  for (int w = 0; w < 4; ++w) wb += (w < wave) ? wtot[w] : 0;
  int total = (wtot[0] + wtot[1]) + (wtot[2] + wtot[3]);
  // export per-s count for the feat pairing (before any early return)
  if (ks == 0 && cb == 0 && rt == 0 && t == 0) scnt[s] = total;
  int lo = rt * TR;
  int nrows = min(TR, total - lo);       // uniform across block
  if (nrows <= 0) return;
  if (t >= nrows && t < TR) rowsL[t] = 0;  // dummy rows for staging reads (stores guarded)
  int pos = wb + scan - cnt8;            // exclusive prefix = rank of this thread's 1st match
#pragma unroll
  for (int i = 0; i < 8; ++i) {
    if (fl[i]) {
      int rel = pos - lo;
      if (rel >= 0 && rel < TR) rowsL[rel] = t * 8 + i;
      pos++;
    }
  }
  __syncthreads();
  // export this tile's slice of the per-s sorted atom order (44 writer blocks)
  if (ks == 0 && cb == 0 && t < nrows) sorted[s * SORT_PITCH + lo + t] = rowsL[t];

  // ---- 64 x 128 tile GEMM over this ks K-slice (4x8 register tile) ----
  __shared__ float As[KT][TR + 4];   // stride 68: 16B-aligned rows, 2-way aliasing (free)
  __shared__ float Bs[KT][TC];       // quads read at tx*4 and 64+tx*4: 2-way (free)

  int ar = t >> 2;        // A row staged by this thread
  int aq = t & 3;         // k-quad within KT chunk
  const float* aSrc = rep + (size_t)rowsL[ar] * R_DIM + ks * KSPAN + aq * 4;
  int kb = t >> 4;        // B k row
  int cc = (t & 15) * 4;  // B col quad (plus +64 partner)
  const float* bSrc = reductors + ((size_t)s * R_DIM + ks * KSPAN + kb) * P_DIM + cb * TC + cc;

  int ty = t >> 4, tx = t & 15;
  int r0 = ty * 4;
  int c0 = tx * 4;        // cols c0..c0+3 and c0+64..c0+67

  float acc[4][8];
#pragma unroll
  for (int i = 0; i < 4; ++i)
#pragma unroll
    for (int j = 0; j < 8; ++j) acc[i][j] = 0.f;

  float4 a  = *(const float4*)aSrc;
  float4 b0 = *(const float4*)bSrc;
  float4 b1 = *(const float4*)(bSrc + 64);

#pragma unroll 1
  for (int k0 = 0; k0 < KSPAN; k0 += KT) {
    __syncthreads();   // previous iteration's LDS reads complete
    As[aq * 4 + 0][ar] = a.x;
    As[aq * 4 + 1][ar] = a.y;
    As[aq * 4 + 2][ar] = a.z;
    As[aq * 4 + 3][ar] = a.w;
    *(float4*)&Bs[kb][cc] = b0;
    *(float4*)&Bs[kb][cc + 64] = b1;
    __syncthreads();
    if (k0 + KT < KSPAN) {   // prefetch next chunk; latency overlaps compute below
      a  = *(const float4*)(aSrc + k0 + KT);
      b0 = *(const float4*)(bSrc + (size_t)(k0 + KT) * P_DIM);
      b1 = *(const float4*)(bSrc + (size_t)(k0 + KT) * P_DIM + 64);
    }
#pragma unroll
    for (int kk = 0; kk < KT; ++kk) {
      float4 aV = *(const float4*)&As[kk][r0];
      float4 bA = *(const float4*)&Bs[kk][c0];
      float4 bB = *(const float4*)&Bs[kk][c0 + 64];
      float av[4] = {aV.x, aV.y, aV.z, aV.w};
      float bv[8] = {bA.x, bA.y, bA.z, bA.w, bB.x, bB.y, bB.z, bB.w};
#pragma unroll
      for (int i = 0; i < 4; ++i)
#pragma unroll
        for (int j = 0; j < 8; ++j) acc[i][j] = fmaf(av[i], bv[j], acc[i][j]);
    }
  }

  // coalesced: 16 threads (tx) cover each 256B half-row segment
#pragma unroll
  for (int i = 0; i < 4; ++i) {
    int r = r0 + i;
    if (r < nrows) {
      float* dst = projp + ((size_t)ks * NATOMS + rowsL[r]) * P_DIM + cb * TC + c0;
      *(float4*)dst = make_float4(acc[i][0], acc[i][1], acc[i][2], acc[i][3]);
      *(float4*)(dst + 64) = make_float4(acc[i][4], acc[i][5], acc[i][6], acc[i][7]);
    }
  }
}

// grid: 4*352 blocks; block (s, pr) handles sorted same-charge atoms 2pr, 2pr+1.
// wave w handles stacks [w*8, w*8+8) for BOTH atoms — d/bi/al loaded once.
__global__ __launch_bounds__(256) void sorf_feat_kernel(
    const float* __restrict__ projp, const int* __restrict__ scnt,
    const int* __restrict__ sorted, const float* __restrict__ Dmat,
    const float* __restrict__ bias, const float* __restrict__ alpha,
    float* __restrict__ out) {
  const int s  = blockIdx.x / PAIRS_PER_S;
  const int pr = blockIdx.x % PAIRS_PER_S;
  const int cntS = scnt[s];
  const int slot0 = pr * 2;
  if (slot0 >= cntS) return;            // uniform: whole block exits
  const bool v1 = (slot0 + 1) < cntS;
  const int atom0 = sorted[s * SORT_PITCH + slot0];
  const int atom1 = v1 ? sorted[s * SORT_PITCH + slot0 + 1] : atom0;

  const int t = threadIdx.x;
  const int lane = t & 63;
  const int wave = t >> 6;

  // lane holds p = 4*lane+k; reduce the KS K-split partials in-register
  float4 p0 = *((const float4*)(projp + (size_t)atom0 * P_DIM) + lane);
  float4 p1 = *((const float4*)(projp + (size_t)atom1 * P_DIM) + lane);
#pragma unroll
  for (int ksi = 1; ksi < KS; ++ksi) {
    float4 q0 = *((const float4*)(projp + ((size_t)ksi * NATOMS + atom0) * P_DIM) + lane);
    float4 q1 = *((const float4*)(projp + ((size_t)ksi * NATOMS + atom1) * P_DIM) + lane);
    p0.x += q0.x; p0.y += q0.y; p0.z += q0.z; p0.w += q0.w;
    p1.x += q1.x; p1.y += q1.y; p1.z += q1.z; p1.w += q1.w;
  }

  const float sg1  = (lane & 1)  ? -1.f : 1.f;
  const float sg2  = (lane & 2)  ? -1.f : 1.f;
  const float sg4  = (lane & 4)  ? -1.f : 1.f;
  const float sg8  = (lane & 8)  ? -1.f : 1.f;
  const float sg16 = (lane & 16) ? -1.f : 1.f;
  const float sg32 = (lane & 32) ? -1.f : 1.f;
  const bool hi4 = (lane & 4) != 0;

  const float* Db = Dmat + (size_t)s * (NSTACKS * P_DIM);
  const float* bb = bias + (size_t)s * F_DIM;
  float accum0 = 0.f, accum1 = 0.f;

#pragma unroll 2
  for (int j = wave * 8; j < wave * 8 + 8; ++j) {
    float4 d  = *((const float4*)(Db + j * P_DIM) + lane);
    float4 bi = *((const float4*)(bb + j * P_DIM) + lane);
    float4 al = *((const float4*)(alpha + j * P_DIM) + lane);
    float x0 = (d.x >= 0.f) ? p0.x : -p0.x;
    float x1 = (d.y >= 0.f) ? p0.y : -p0.y;
    float x2 = (d.z >= 0.f) ? p0.z : -p0.z;
    float x3 = (d.w >= 0.f) ? p0.w : -p0.w;
    float u0 = (d.x >= 0.f) ? p1.x : -p1.x;
    float u1 = (d.y >= 0.f) ? p1.y : -p1.y;
    float u2 = (d.z >= 0.f) ? p1.z : -p1.z;
    float u3 = (d.w >= 0.f) ? p1.w : -p1.w;
    // FWHT bits 0,1 in-register (both chains — independent, 2-way ILP)
    { float t0 = x0 + x1, t1 = x0 - x1, t2 = x2 + x3, t3 = x2 - x3;
      x0 = t0 + t2; x2 = t0 - t2; x1 = t1 + t3; x3 = t1 - t3; }
    { float t0 = u0 + u1, t1 = u0 - u1, t2 = u2 + u3, t3 = u2 - u3;
      u0 = t0 + t2; u2 = t0 - t2; u1 = t1 + t3; u3 = t1 - t3; }
    // xor1 (DPP)
    { float y0 = DPPF(x0, 0xB1), y1 = DPPF(x1, 0xB1), y2 = DPPF(x2, 0xB1), y3 = DPPF(x3, 0xB1);
      float z0 = DPPF(u0, 0xB1), z1 = DPPF(u1, 0xB1), z2 = DPPF(u2, 0xB1), z3 = DPPF(u3, 0xB1);
      x0 = fmaf(sg1, x0, y0); x1 = fmaf(sg1, x1, y1);
      x2 = fmaf(sg1, x2, y2); x3 = fmaf(sg1, x3, y3);
      u0 = fmaf(sg1, u0, z0); u1 = fmaf(sg1, u1, z1);
      u2 = fmaf(sg1, u2, z2); u3 = fmaf(sg1, u3, z3); }
    // xor2 (DPP)
    { float y0 = DPPF(x0, 0x4E), y1 = DPPF(x1, 0x4E), y2 = DPPF(x2, 0x4E), y3 = DPPF(x3, 0x4E);
      float z0 = DPPF(u0, 0x4E), z1 = DPPF(u1, 0x4E), z2 = DPPF(u2, 0x4E), z3 = DPPF(u3, 0x4E);
      x0 = fmaf(sg2, x0, y0); x1 = fmaf(sg2, x1, y1);
      x2 = fmaf(sg2, x2, y2); x3 = fmaf(sg2, x3, y3);
      u0 = fmaf(sg2, u0, z0); u1 = fmaf(sg2, u1, z1);
      u2 = fmaf(sg2, u2, z2); u3 = fmaf(sg2, u3, z3); }
    // xor4: both DPP shifts unconditionally, branchless select (validated R7)
    { float a0 = DPPF(x0, 0x104), a1 = DPPF(x1, 0x104), a2 = DPPF(x2, 0x104), a3 = DPPF(x3, 0x104);
      float b0 = DPPF(x0, 0x114), b1 = DPPF(x1, 0x114), b2 = DPPF(x2, 0x114), b3 = DPPF(x3, 0x114);
      float y0 = hi4 ? b0 : a0;
      float y1 = hi4 ? b1 : a1;
      float y2 = hi4 ? b2 : a2;
      float y3 = hi4 ? b3 : a3;
      x0 = fmaf(sg4, x0, y0); x1 = fmaf(sg4, x1, y1);
      x2 = fmaf(sg4, x2, y2); x3 = fmaf(sg4, x3, y3); }
    { float a0 = DPPF(u0, 0x104), a1 = DPPF(u1, 0x104), a2 = DPPF(u2, 0x104), a3 = DPPF(u3, 0x104);
      float b0 = DPPF(u0, 0x114), b1 = DPPF(u1, 0x114), b2 = DPPF(u2, 0x114), b3 = DPPF(u3, 0x114);
      float z0 = hi4 ? b0 : a0;
      float z1 = hi4 ? b1 : a1;
      float z2 = hi4 ? b2 : a2;
      float z3 = hi4 ? b3 : a3;
      u0 = fmaf(sg4, u0, z0); u1 = fmaf(sg4, u1, z1);
      u2 = fmaf(sg4, u2, z2); u3 = fmaf(sg4, u3, z3); }
    // xor8 (DPP row_ror:8)
    { float y0 = DPPF(x0, 0x128), y1 = DPPF(x1, 0x128), y2 = DPPF(x2, 0x128), y3 = DPPF(x3, 0x128);
      float z0 = DPPF(u0, 0x128), z1 = DPPF(u1, 0x128), z2 = DPPF(u2, 0x128), z3 = DPPF(u3, 0x128);
      x0 = fmaf(sg8, x0, y0); x1 = fmaf(sg8, x1, y1);
      x2 = fmaf(sg8, x2, y2); x3 = fmaf(sg8, x3, y3);
      u0 = fmaf(sg8, u0, z0); u1 = fmaf(sg8, u1, z1);
      u2 = fmaf(sg8, u2, z2); u3 = fmaf(sg8, u3, z3); }
    // xor16 (v_permlane16_swap_b32 — VALU, no LDS pipe)
    x0 = bfly16(x0, sg16); x1 = bfly16(x1, sg16);
    x2 = bfly16(x2, sg16); x3 = bfly16(x3, sg16);
    u0 = bfly16(u0, sg16); u1 = bfly16(u1, sg16);
    u2 = bfly16(u2, sg16); u3 = bfly16(u3, sg16);
    // xor32 (v_permlane32_swap_b32 — VALU, no LDS pipe)
    x0 = bfly32(x0, sg32); x1 = bfly32(x1, sg32);
    x2 = bfly32(x2, sg32); x3 = bfly32(x3, sg32);
    u0 = bfly32(u0, sg32); u1 = bfly32(u1, sg32);
    u2 = bfly32(u2, sg32); u3 = bfly32(u3, sg32);
    // fwht norm 1/16; COEFF_NORM = 1.0 exactly
    accum0 += __cosf(fmaf(x0, 0.0625f, bi.x)) * al.x;
    accum0 += __cosf(fmaf(x1, 0.0625f, bi.y)) * al.y;
    accum0 += __cosf(fmaf(x2, 0.0625f, bi.z)) * al.z;
    accum0 += __cosf(fmaf(x3, 0.0625f, bi.w)) * al.w;
    accum1 += __cosf(fmaf(u0, 0.0625f, bi.x)) * al.x;
    accum1 += __cosf(fmaf(u1, 0.0625f, bi.y)) * al.y;
    accum1 += __cosf(fmaf(u2, 0.0625f, bi.z)) * al.z;
    accum1 += __cosf(fmaf(u3, 0.0625f, bi.w)) * al.w;
  }

  // wave sum-reduce (permutation-invariant), both atoms
  accum0 += DPPF(accum0, 0xB1);
  accum0 += DPPF(accum0, 0x4E);
  accum0 += DPPF(accum0, 0x124);   // row_ror:4
  accum0 += DPPF(accum0, 0x128);   // row_ror:8
  accum0 = redsum16(accum0);
  accum0 = redsum32(accum0);
  accum1 += DPPF(accum1, 0xB1);
  accum1 += DPPF(accum1, 0x4E);
  accum1 += DPPF(accum1, 0x124);
  accum1 += DPPF(accum1, 0x128);
  accum1 = redsum16(accum1);
  accum1 = redsum32(accum1);

  __shared__ float wsum0[4], wsum1[4];
  if (lane == 0) { wsum0[wave] = accum0; wsum1[wave] = accum1; }
  __syncthreads();
  if (t == 0) {
    // FEAT_NORM = 1/64 exactly
    atomicAdd(out + (atom0 >> 6),
              0.015625f * ((wsum0[0] + wsum0[1]) + (wsum0[2] + wsum0[3])));
    if (v1)
      atomicAdd(out + (atom1 >> 6),
                0.015625f * ((wsum1[0] + wsum1[1]) + (wsum1[2] + wsum1[3])));
  }
}

extern "C" void kernel_launch(void* const* d_in, const int* in_sizes, int n_in,
                              void* d_out, int out_size, void* d_ws, size_t ws_size,
                              hipStream_t stream) {
  const float* rep       = (const float*)d_in[0];
  const int*   charges   = (const int*)d_in[1];
  const float* reductors = (const float*)d_in[2];
  const float* Dmat      = (const float*)d_in[3];
  const float* bias      = (const float*)d_in[4];
  const float* alpha     = (const float*)d_in[5];
  float* out = (float*)d_out;

  int*   scnt   = (int*)d_ws;
  int*   sorted = (int*)((char*)d_ws + 64);
  float* projp  = (float*)((char*)d_ws + 16384);

  sorf_proj_kernel<<<8 * 2 * RT_TILES * S_DIM, 256, 0, stream>>>(
      rep, reductors, charges, projp, scnt, sorted, out);
  sorf_feat_kernel<<<S_DIM * PAIRS_PER_S, 256, 0, stream>>>(
      projp, scnt, sorted, Dmat, bias, alpha, out);
}